// Round 5
// baseline (30142.764 us; speedup 1.0000x reference)
//
#include <hip/hip_runtime.h>
#include <hip/hip_bf16.h>

typedef __hip_bfloat16 bf16;

#define TSTEPS 256
#define NB 16
#define HID 4096
#define PRJ 512
#define G4H 16384
#define MR 4096      // TSTEPS*NB
#define TCHUNK 64
#define MCH (TCHUNK * NB)   // 1024 rows per gemm chunk

__device__ __forceinline__ float sigm(float x) { return 1.f / (1.f + expf(-x)); }
__device__ __forceinline__ float ldx(const float* p) { return *p; }
__device__ __forceinline__ float ldx(const bf16* p) { return __bfloat162float(*p); }

// ---------------- zero h/c ----------------
__global__ void zero_hc(float* h, float* c) {
    int i = blockIdx.x * 256 + threadIdx.x;
    if (i < NB * PRJ) h[i] = 0.f;
    if (i < NB * HID) c[i] = 0.f;
}

// ---------------- copy con_x (f32) into x2 (bf16) [:, 512:1280] ----------------
__global__ void con_copy(const float* __restrict__ con, bf16* __restrict__ x2) {
    int i = blockIdx.x * 256 + threadIdx.x;
    const int total = MR * 768;
    if (i < total) {
        int row = i / 768, cc = i % 768;
        x2[(size_t)row * 1280 + 512 + cc] = __float2bfloat16(con[i]);
    }
}

// ---------------- copy final states to d_out (f32) ----------------
__global__ void copy_state(const float* __restrict__ h, const float* __restrict__ c,
                           float* __restrict__ dh, float* __restrict__ dc) {
    int i = blockIdx.x * 256 + threadIdx.x;
    if (i < NB * PRJ) dh[i] = h[i];
    if (i < NB * HID) dc[i] = c[i];
}

// ---------------- xg = X @ W^T + bias, bf16 out ----------------
// X: [MCH, K] (f32 or bf16) row-major; W: [G4H, K] f32; out: [MCH, G4H] bf16
template <int K, typename XT>
__global__ __launch_bounds__(256)
void gemm_xg(const XT* __restrict__ X, const float* __restrict__ W,
             const float* __restrict__ bias, bf16* __restrict__ out) {
    const int BK = 16;
    __shared__ float As[BK][68];
    __shared__ float Bs[BK][68];
    const int bm = blockIdx.y * 64;
    const int bn = blockIdx.x * 64;
    const int tid = threadIdx.x;
    const int tx = tid % 16;      // n
    const int ty = tid / 16;      // m
    float acc[4][4] = {};
    const int nkt = (K + BK - 1) / BK;
    for (int kt = 0; kt < nkt; ++kt) {
        const int k0 = kt * BK;
#pragma unroll
        for (int i = 0; i < 4; ++i) {
            int idx = tid + i * 256;
            int kk = idx % BK;
            int mm = idx / BK;
            int k = k0 + kk;
            float v = 0.f;
            if (k < K) v = ldx(&X[(size_t)(bm + mm) * K + k]);
            As[kk][mm] = v;
        }
#pragma unroll
        for (int i = 0; i < 4; ++i) {
            int idx = tid + i * 256;
            int kk = idx % BK;
            int nn = idx / BK;
            int k = k0 + kk;
            float v = 0.f;
            if (k < K) v = W[(size_t)(bn + nn) * K + k];
            Bs[kk][nn] = v;
        }
        __syncthreads();
#pragma unroll
        for (int kk = 0; kk < BK; ++kk) {
            float4 a4 = *(const float4*)&As[kk][ty * 4];
            float4 b4 = *(const float4*)&Bs[kk][tx * 4];
            float a[4] = {a4.x, a4.y, a4.z, a4.w};
            float bb[4] = {b4.x, b4.y, b4.z, b4.w};
#pragma unroll
            for (int i = 0; i < 4; ++i)
#pragma unroll
                for (int j = 0; j < 4; ++j)
                    acc[i][j] += a[i] * bb[j];
        }
        __syncthreads();
    }
#pragma unroll
    for (int i = 0; i < 4; ++i) {
        int m = bm + ty * 4 + i;
#pragma unroll
        for (int j = 0; j < 4; ++j) {
            int n = bn + tx * 4 + j;
            out[(size_t)m * G4H + n] = __float2bfloat16(acc[i][j] + bias[n]);
        }
    }
}

// ---------------- per-step gates: z = xg_t + h @ Whh^T, c/htmp update ----------------
__global__ __launch_bounds__(256)
void gate_kernel(const bf16* __restrict__ xg_t, const float* __restrict__ Whh,
                 const float* __restrict__ h, float* __restrict__ c,
                 float* __restrict__ htmp) {
    __shared__ float hs[NB][516];
    const int tid = threadIdx.x;
    for (int i = tid; i < NB * PRJ; i += 256) {
        hs[i / PRJ][i % PRJ] = h[i];
    }
    __syncthreads();
    const int b = tid % 16;
    const int u = blockIdx.x * 16 + tid / 16;  // 0..4095
    const float* w0 = Whh + (size_t)(u) * PRJ;
    const float* w1 = Whh + (size_t)(u + 4096) * PRJ;
    const float* w2 = Whh + (size_t)(u + 8192) * PRJ;
    const float* w3 = Whh + (size_t)(u + 12288) * PRJ;
    float ai = 0.f, af = 0.f, ag = 0.f, ao = 0.f;
#pragma unroll 4
    for (int k = 0; k < PRJ; k += 4) {
        float4 hv = *(const float4*)&hs[b][k];
        float4 vi = *(const float4*)&w0[k];
        float4 vf = *(const float4*)&w1[k];
        float4 vg = *(const float4*)&w2[k];
        float4 vo = *(const float4*)&w3[k];
        ai += hv.x * vi.x + hv.y * vi.y + hv.z * vi.z + hv.w * vi.w;
        af += hv.x * vf.x + hv.y * vf.y + hv.z * vf.z + hv.w * vf.w;
        ag += hv.x * vg.x + hv.y * vg.y + hv.z * vg.z + hv.w * vg.w;
        ao += hv.x * vo.x + hv.y * vo.y + hv.z * vo.z + hv.w * vo.w;
    }
    const size_t xb = (size_t)b * G4H;
    float zi = ai + __bfloat162float(xg_t[xb + u]);
    float zf = af + __bfloat162float(xg_t[xb + 4096 + u]);
    float zg = ag + __bfloat162float(xg_t[xb + 8192 + u]);
    float zo = ao + __bfloat162float(xg_t[xb + 12288 + u]);
    const int ci = b * HID + u;
    float cn = sigm(zf) * c[ci] + sigm(zi) * tanhf(zg);
    c[ci] = cn;
    htmp[ci] = sigm(zo) * tanhf(cn);
}

// ---------------- projection: h = htmp @ Whr^T ----------------
// writes h (f32) and dest (bf16) at dest[b*stride + p]
__global__ __launch_bounds__(256)
void proj_kernel(const float* __restrict__ htmp, const float* __restrict__ Whr,
                 float* __restrict__ h, bf16* __restrict__ dest, int dest_stride) {
    const int wave = threadIdx.x / 64;
    const int lane = threadIdx.x % 64;
    const int p = blockIdx.x * 4 + wave;  // grid 128 -> p<512
    const float* wr = Whr + (size_t)p * HID;
    float acc[NB] = {};
    for (int k = lane * 4; k < HID; k += 256) {
        float4 w = *(const float4*)&wr[k];
#pragma unroll
        for (int b = 0; b < NB; ++b) {
            float4 hv = *(const float4*)&htmp[(size_t)b * HID + k];
            acc[b] += hv.x * w.x + hv.y * w.y + hv.z * w.z + hv.w * w.w;
        }
    }
#pragma unroll
    for (int b = 0; b < NB; ++b) {
        float v = acc[b];
#pragma unroll
        for (int off = 32; off; off >>= 1) v += __shfl_xor(v, off);
        if (lane == 0) {
            h[b * PRJ + p] = v;
            dest[(size_t)b * dest_stride + p] = __float2bfloat16(v);
        }
    }
}

// ---------------- packing offsets from seq_lens ----------------
__global__ void offsets_kernel(const int* __restrict__ lens, int* __restrict__ offs) {
    __shared__ int cnt[TSTEPS];
    int t = threadIdx.x;
    int cc = 0;
    for (int b = 0; b < NB; ++b) cc += (lens[b] > t) ? 1 : 0;
    cnt[t] = cc;
    __syncthreads();
    if (t == 0) {
        int s = 0;
        for (int i = 0; i < TSTEPS; ++i) { offs[i] = s; s += cnt[i]; }
        offs[TSTEPS] = s;
    }
}

// ---------------- heads: resid -> pssm(softmax), aa (f32 out) ----------------
__global__ __launch_bounds__(64)
void head_kernel(const bf16* __restrict__ x2, const bf16* __restrict__ out2,
                 const int* __restrict__ lens, const int* __restrict__ offs,
                 const float* __restrict__ Wp, const float* __restrict__ bp,
                 const float* __restrict__ Wa, const float* __restrict__ ba,
                 float* __restrict__ pssm, float* __restrict__ aa) {
    const int t = blockIdx.x / NB;
    const int b = blockIdx.x % NB;
    if (t >= lens[b]) return;
    const int row = t * NB + b;
    const int lane = threadIdx.x;
    float r[8];
    const bf16* o1 = x2 + (size_t)row * 1280;
    const bf16* o2 = out2 + (size_t)row * PRJ;
#pragma unroll
    for (int i = 0; i < 8; ++i)
        r[i] = __bfloat162float(o1[lane * 8 + i]) + __bfloat162float(o2[lane * 8 + i]);
    const int pi = offs[t] + b;

    float lg[20];
#pragma unroll
    for (int o = 0; o < 20; ++o) {
        const float* w = Wp + o * PRJ;
        float s = 0.f;
#pragma unroll
        for (int i = 0; i < 8; ++i) s += r[i] * w[lane * 8 + i];
#pragma unroll
        for (int off = 32; off; off >>= 1) s += __shfl_xor(s, off);
        lg[o] = s + bp[o];
    }
    float mx = lg[0];
#pragma unroll
    for (int o = 1; o < 20; ++o) mx = fmaxf(mx, lg[o]);
    float se = 0.f;
#pragma unroll
    for (int o = 0; o < 20; ++o) { lg[o] = expf(lg[o] - mx); se += lg[o]; }
    float inv = 1.f / se;
#pragma unroll
    for (int o = 0; o < 20; ++o) {
        if (lane == o) pssm[(size_t)pi * 20 + o] = lg[o] * inv;
    }
#pragma unroll
    for (int o = 0; o < 20; ++o) {
        const float* w = Wa + o * PRJ;
        float s = 0.f;
#pragma unroll
        for (int i = 0; i < 8; ++i) s += r[i] * w[lane * 8 + i];
#pragma unroll
        for (int off = 32; off; off >>= 1) s += __shfl_xor(s, off);
        if (lane == o) aa[(size_t)pi * 20 + o] = s + ba[o];
    }
}

extern "C" void kernel_launch(void* const* d_in, const int* in_sizes, int n_in,
                              void* d_out, int out_size, void* d_ws, size_t ws_size,
                              hipStream_t stream) {
    const float* uncon = (const float*)d_in[0];
    const float* con   = (const float*)d_in[1];
    const int*   lens  = (const int*)d_in[2];
    const float* Wih1  = (const float*)d_in[3];
    const float* b1    = (const float*)d_in[4];
    const float* Whh1  = (const float*)d_in[5];
    const float* Whr1  = (const float*)d_in[6];
    const float* Wih2  = (const float*)d_in[7];
    const float* b2    = (const float*)d_in[8];
    const float* Whh2  = (const float*)d_in[9];
    const float* Whr2  = (const float*)d_in[10];
    const float* Wp    = (const float*)d_in[11];
    const float* bp    = (const float*)d_in[12];
    const float* Wa    = (const float*)d_in[13];
    const float* ba    = (const float*)d_in[14];

    // ---- workspace layout: total ~46.6 MiB ----
    char* ws = (char*)d_ws;
    size_t o = 0;
    bf16*  xgc  = (bf16*)(ws + o);  o += (size_t)MCH * G4H * 2;   // 32 MiB
    bf16*  x2   = (bf16*)(ws + o);  o += (size_t)MR * 1280 * 2;   // 10 MiB
    bf16*  out2 = (bf16*)(ws + o);  o += (size_t)MR * PRJ * 2;    // 4 MiB
    float* h    = (float*)(ws + o); o += (size_t)NB * PRJ * 4;
    float* c    = (float*)(ws + o); o += (size_t)NB * HID * 4;
    float* htmp = (float*)(ws + o); o += (size_t)NB * HID * 4;
    int*   offs = (int*)(ws + o);   o += 4096;

    // ---- d_out is FLOAT32 (reference outputs are f32) ----
    float* out = (float*)d_out;
    size_t tok = ((size_t)out_size - 147456) / 40;
    float* o_pssm = out;
    float* o_aa   = out + tok * 20;
    float* o_h1   = out + tok * 40;
    float* o_c1   = o_h1 + NB * PRJ;
    float* o_h2   = o_c1 + NB * HID;
    float* o_c2   = o_h2 + NB * PRJ;

    // ---- layer 1 (chunked xg precompute) ----
    zero_hc<<<dim3(288), dim3(256), 0, stream>>>(h, c);
    con_copy<<<dim3((MR * 768 + 255) / 256), dim3(256), 0, stream>>>(con, x2);
    for (int tc = 0; tc < TSTEPS; tc += TCHUNK) {
        gemm_xg<532, float><<<dim3(256, MCH / 64), dim3(256), 0, stream>>>(
            uncon + (size_t)tc * NB * 532, Wih1, b1, xgc);
        for (int t = tc; t < tc + TCHUNK; ++t) {
            gate_kernel<<<dim3(256), dim3(256), 0, stream>>>(
                xgc + (size_t)(t - tc) * NB * G4H, Whh1, h, c, htmp);
            proj_kernel<<<dim3(128), dim3(256), 0, stream>>>(
                htmp, Whr1, h, x2 + (size_t)t * NB * 1280, 1280);
        }
    }
    copy_state<<<dim3(288), dim3(256), 0, stream>>>(h, c, o_h1, o_c1);

    // ---- layer 2 ----
    zero_hc<<<dim3(288), dim3(256), 0, stream>>>(h, c);
    for (int tc = 0; tc < TSTEPS; tc += TCHUNK) {
        gemm_xg<1280, bf16><<<dim3(256, MCH / 64), dim3(256), 0, stream>>>(
            x2 + (size_t)tc * NB * 1280, Wih2, b2, xgc);
        for (int t = tc; t < tc + TCHUNK; ++t) {
            gate_kernel<<<dim3(256), dim3(256), 0, stream>>>(
                xgc + (size_t)(t - tc) * NB * G4H, Whh2, h, c, htmp);
            proj_kernel<<<dim3(128), dim3(256), 0, stream>>>(
                htmp, Whr2, h, out2 + (size_t)t * NB * PRJ, PRJ);
        }
    }
    copy_state<<<dim3(288), dim3(256), 0, stream>>>(h, c, o_h2, o_c2);

    // ---- heads ----
    offsets_kernel<<<dim3(1), dim3(256), 0, stream>>>(lens, offs);
    head_kernel<<<dim3(MR), dim3(64), 0, stream>>>(
        x2, out2, lens, offs, Wp, bp, Wa, ba, o_pssm, o_aa);
}